// Round 5
// baseline (64.915 us; speedup 1.0000x reference)
//
#include <hip/hip_runtime.h>
#include <hip/hip_bf16.h>

typedef short short8 __attribute__((ext_vector_type(8)));
typedef float f32x4 __attribute__((ext_vector_type(4)));

#define INV_SQRT2F 0.70710678118654752440f

__device__ __forceinline__ unsigned short f2bf(float f) {
  union { float f; unsigned u; } v; v.f = f;
  unsigned u = v.u;
  unsigned r = (u + 0x7FFFu + ((u >> 16) & 1u)) >> 16;  // RNE
  return (unsigned short)r;
}

// ---------------------------------------------------------------------------
// Precompute: W'[e,:] = inverse Haar transform of W[e,:]  (since out = (W H) x),
// packed as bf16 in MFMA B-fragment layout:
//   flat bf16 index = ((nblk*8 + kk)*64 + lane)*8 + j
//   where e = nblk*16 + (lane&15), k = kk*32 + (lane>>4)*8 + j
// ---------------------------------------------------------------------------
__global__ void haar_pack(const float* __restrict__ W, unsigned short* __restrict__ Wp) {
  __shared__ float cbuf[4][256];
  __shared__ float buf0[4][256];
  __shared__ float buf1[4][256];
  const int tid = threadIdx.x;
  const int w = tid >> 6, l = tid & 63;
  const int e = blockIdx.x * 4 + w;
  const float* row = W + e * 256;
  for (int k = l; k < 256; k += 64) cbuf[w][k] = row[k];
  __syncthreads();
  if (l == 0) buf0[w][0] = cbuf[w][0];   // a = [cA_8]
  __syncthreads();
  float* A = buf0[w];
  float* Bv = buf1[w];
  int len = 1;
  // coeff layout: [cA_8(1), cD_8(1), cD_7(2), ..., cD_1(128)]; offset(cD_lev)=len
  for (int s = 0; s < 8; ++s) {
    for (int k = l; k < len; k += 64) {
      float av = A[k], dv = cbuf[w][len + k];
      Bv[2 * k]     = (av + dv) * INV_SQRT2F;   // even
      Bv[2 * k + 1] = (av - dv) * INV_SQRT2F;   // odd
    }
    __syncthreads();
    float* t = A; A = Bv; Bv = t;
    len <<= 1;
  }
  const int nblk = e >> 4, lr = e & 15;
  for (int k = l; k < 256; k += 64) {
    int kk = k >> 5, win = k & 31, lhi = win >> 3, j = win & 7;
    int lane = lhi * 16 + lr;
    Wp[(((nblk * 8 + kk) * 64 + lane) << 3) + j] = f2bf(A[k]);
  }
}

// ---------------------------------------------------------------------------
// Persistent-block streaming GEMM: out[m,e] = sum_k x[m,k] W'[e,k] + b[e]
// - B fragments live in REGISTERS (32 short8 = 128 VGPR per wave, static
//   indices), loaded once per block from L2. LDS is A-only.
// - 8 waves (2 wm x 4 wn), wave tile 16 rows x 64 cols; 32-row tiles,
//   double-buffered A LDS (2 x 16 KB), ONE barrier per iteration.
// - Per wave-iter: 8 ds_read_b128 (A) + 32 MFMA + 4 float4 prefetch +
//   16 nontemporal dword stores. LDS/CU/iter ~770 cyc << ~6100 cyc BW budget.
// - A tile XOR-swizzled: byte ^= (row&7)<<4 (conflict-free b128 reads).
// ---------------------------------------------------------------------------
#define NTILES 16
#define BM 32

__global__ __launch_bounds__(512, 2) void wemb_gemm(
    const float* __restrict__ x, const unsigned short* __restrict__ Wp,
    const float* __restrict__ bias, float* __restrict__ out) {
  __shared__ char al[2][16384];
  const int tid = threadIdx.x;
  const int w = tid >> 6, lane = tid & 63;
  const int wm = w >> 2, wn = w & 3;      // 2 x 4 wave grid
  const int lr = lane & 15, lhi = lane >> 4;

  // ---- B fragments -> registers (L2-hot after block 0; 32 KB/wave) ----
  short8 Bf[8][4];   // [kk][n], all indices compile-time in the loop below
#pragma unroll
  for (int kk = 0; kk < 8; ++kk)
#pragma unroll
    for (int n = 0; n < 4; ++n)
      Bf[kk][n] = *(const short8*)(Wp + ((((wn * 4 + n) * 8 + kk) * 64 + lane) << 3));

  float bv[4];
#pragma unroll
  for (int n = 0; n < 4; ++n) bv[n] = bias[wn * 64 + n * 16 + lr];

  const long tile0 = (long)blockIdx.x * NTILES;

  // ---- prologue: stage tile 0 into al[0] ----
  {
    const float4* src = (const float4*)(x + tile0 * (BM * 256));
#pragma unroll
    for (int i = 0; i < 4; ++i) {
      int f = i * 512 + tid;
      float4 v = src[f];
      int row = f >> 6, colb = (f & 63) * 8;
      ushort4 p; p.x = f2bf(v.x); p.y = f2bf(v.y); p.z = f2bf(v.z); p.w = f2bf(v.w);
      *(ushort4*)(al[0] + row * 512 + (colb ^ ((row & 7) << 4))) = p;
    }
  }
  __syncthreads();

#pragma unroll 1
  for (int it = 0; it < NTILES; ++it) {
    const long tt = tile0 + it;
    char* cur = al[it & 1];
    char* nxt = al[(it & 1) ^ 1];

    // ---- issue prefetch of next tile (latency hides under compute+stores) ----
    float4 pf[4];
    if (it < NTILES - 1) {
      const float4* src = (const float4*)(x + (tt + 1) * (BM * 256));
#pragma unroll
      for (int i = 0; i < 4; ++i) pf[i] = src[i * 512 + tid];
    }

    // ---- compute: A from LDS, B from registers ----
    f32x4 acc[4];
#pragma unroll
    for (int n = 0; n < 4; ++n) acc[n] = (f32x4){0.f, 0.f, 0.f, 0.f};
#pragma unroll
    for (int kk = 0; kk < 8; ++kk) {
      const int arow = wm * 16 + lr;
      const int colb = (kk * 32 + lhi * 8) * 2;
      short8 a = *(const short8*)(cur + arow * 512 + (colb ^ ((arow & 7) << 4)));
#pragma unroll
      for (int n = 0; n < 4; ++n)
        acc[n] = __builtin_amdgcn_mfma_f32_16x16x32_bf16(a, Bf[kk][n], acc[n], 0, 0, 0);
    }

    // ---- store this tile (nontemporal: write-once stream, keep L3 for x) ----
    {
      float* orow = out + (tt * BM + wm * 16 + lhi * 4) * 256;
#pragma unroll
      for (int n = 0; n < 4; ++n) {
        const int e = wn * 64 + n * 16 + lr;
#pragma unroll
        for (int r = 0; r < 4; ++r)
          __builtin_nontemporal_store(acc[n][r] + bv[n], orow + r * 256 + e);
      }
    }

    // ---- write next tile into the other buffer; single barrier ----
    if (it < NTILES - 1) {
#pragma unroll
      for (int i = 0; i < 4; ++i) {
        int f = i * 512 + tid;
        int row = f >> 6, colb = (f & 63) * 8;
        ushort4 p; p.x = f2bf(pf[i].x); p.y = f2bf(pf[i].y); p.z = f2bf(pf[i].z); p.w = f2bf(pf[i].w);
        *(ushort4*)(nxt + row * 512 + (colb ^ ((row & 7) << 4))) = p;
      }
    }
    __syncthreads();
  }
}

extern "C" void kernel_launch(void* const* d_in, const int* in_sizes, int n_in,
                              void* d_out, int out_size, void* d_ws, size_t ws_size,
                              hipStream_t stream) {
  const float* x = (const float*)d_in[0];     // (16, 8192, 256) fp32
  const float* W = (const float*)d_in[1];     // (256, 256) fp32
  const float* b = (const float*)d_in[2];     // (256,) fp32
  float* out = (float*)d_out;                 // (16, 8192, 256) fp32
  unsigned short* Wp = (unsigned short*)d_ws; // 256*256 bf16 = 128 KB

  haar_pack<<<64, 256, 0, stream>>>(W, Wp);

  const int grid = (out_size / 256) / (BM * NTILES);  // 131072 / 512 = 256
  wemb_gemm<<<grid, 512, 0, stream>>>(x, Wp, b, out);
}

// Round 6
// 57.340 us; speedup vs baseline: 1.1321x; 1.1321x over previous
//
#include <hip/hip_runtime.h>
#include <hip/hip_bf16.h>

typedef short short8 __attribute__((ext_vector_type(8)));
typedef float f32x4 __attribute__((ext_vector_type(4)));

#define INV_SQRT2F 0.70710678118654752440f

__device__ __forceinline__ unsigned short f2bf(float f) {
  union { float f; unsigned u; } v; v.f = f;
  unsigned u = v.u;
  unsigned r = (u + 0x7FFFu + ((u >> 16) & 1u)) >> 16;  // RNE
  return (unsigned short)r;
}

// ---------------------------------------------------------------------------
// Precompute: W'[e,:] = inverse Haar transform of W[e,:]  (since out = (W H) x),
// packed as bf16 in MFMA B-fragment layout:
//   flat bf16 index = ((nblk*8 + kk)*64 + lane)*8 + j
//   where e = nblk*16 + (lane&15), k = kk*32 + (lane>>4)*8 + j
// ---------------------------------------------------------------------------
__global__ void haar_pack(const float* __restrict__ W, unsigned short* __restrict__ Wp) {
  __shared__ float cbuf[4][256];
  __shared__ float buf0[4][256];
  __shared__ float buf1[4][256];
  const int tid = threadIdx.x;
  const int w = tid >> 6, l = tid & 63;
  const int e = blockIdx.x * 4 + w;
  const float* row = W + e * 256;
  for (int k = l; k < 256; k += 64) cbuf[w][k] = row[k];
  __syncthreads();
  if (l == 0) buf0[w][0] = cbuf[w][0];   // a = [cA_8]
  __syncthreads();
  float* A = buf0[w];
  float* Bv = buf1[w];
  int len = 1;
  // coeff layout: [cA_8(1), cD_8(1), cD_7(2), ..., cD_1(128)]; offset(cD_lev)=len
  for (int s = 0; s < 8; ++s) {
    for (int k = l; k < len; k += 64) {
      float av = A[k], dv = cbuf[w][len + k];
      Bv[2 * k]     = (av + dv) * INV_SQRT2F;   // even
      Bv[2 * k + 1] = (av - dv) * INV_SQRT2F;   // odd
    }
    __syncthreads();
    float* t = A; A = Bv; Bv = t;
    len <<= 1;
  }
  const int nblk = e >> 4, lr = e & 15;
  for (int k = l; k < 256; k += 64) {
    int kk = k >> 5, win = k & 31, lhi = win >> 3, j = win & 7;
    int lane = lhi * 16 + lr;
    Wp[(((nblk * 8 + kk) * 64 + lane) << 3) + j] = f2bf(A[k]);
  }
}

// ---------------------------------------------------------------------------
// Persistent-block streaming GEMM: out[m,e] = sum_k x[m,k] W'[e,k] + b[e]
// - B fragments in REGISTERS, loaded from global ONCE and pinned with an
//   empty asm so the compiler cannot sink the loads into the loop
//   (R5's failure mode: VGPR=100 proved Bf was re-loaded per iter).
// - LDS is A-only: 2 x 16 KB double buffer, ONE barrier per iteration.
// - 8 waves (2 wm x 4 wn), wave tile 16 rows x 64 cols; 16 tiles of 32 rows.
// - Per wave-iter: 8 ds_read_b128 (A) + 32 MFMA + 4 float4 prefetch + 16
//   dword stores. LDS ~770 cyc/CU/iter << ~2600 cyc HBM-pace budget.
// - A tile XOR-swizzled: byte ^= (row&7)<<4 (conflict-free b128 reads).
// ---------------------------------------------------------------------------
#define NTILES 16
#define BM 32

__global__ __launch_bounds__(512, 2) void wemb_gemm(
    const float* __restrict__ x, const unsigned short* __restrict__ Wp,
    const float* __restrict__ bias, float* __restrict__ out) {
  __shared__ char al[2][16384];
  const int tid = threadIdx.x;
  const int w = tid >> 6, lane = tid & 63;
  const int wm = w >> 2, wn = w & 3;      // 2 x 4 wave grid
  const int lr = lane & 15, lhi = lane >> 4;

  // ---- B fragments -> registers, loaded once, pinned ----
  short8 Bf[8][4];   // [kk][n]
#pragma unroll
  for (int kk = 0; kk < 8; ++kk)
#pragma unroll
    for (int n = 0; n < 4; ++n)
      Bf[kk][n] = *(const short8*)(Wp + ((((wn * 4 + n) * 8 + kk) * 64 + lane) << 3));
#pragma unroll
  for (int kk = 0; kk < 8; ++kk)
#pragma unroll
    for (int n = 0; n < 4; ++n)
      asm volatile("" : "+v"(Bf[kk][n]));   // pin: forbids re-load inside loop

  float bv[4];
#pragma unroll
  for (int n = 0; n < 4; ++n) bv[n] = bias[wn * 64 + n * 16 + lr];

  const long tile0 = (long)blockIdx.x * NTILES;

  // ---- prologue: stage tile 0 into al[0] ----
  {
    const float4* src = (const float4*)(x + tile0 * (BM * 256));
#pragma unroll
    for (int i = 0; i < 4; ++i) {
      int f = i * 512 + tid;
      float4 v = src[f];
      int row = f >> 6, colb = (f & 63) * 8;
      ushort4 p;
      p.x = __bfloat16_as_ushort(__float2bfloat16(v.x));
      p.y = __bfloat16_as_ushort(__float2bfloat16(v.y));
      p.z = __bfloat16_as_ushort(__float2bfloat16(v.z));
      p.w = __bfloat16_as_ushort(__float2bfloat16(v.w));
      *(ushort4*)(al[0] + row * 512 + (colb ^ ((row & 7) << 4))) = p;
    }
  }
  __syncthreads();

#pragma unroll 1
  for (int it = 0; it < NTILES; ++it) {
    const long tt = tile0 + it;
    char* cur = al[it & 1];
    char* nxt = al[(it & 1) ^ 1];

    // ---- issue prefetch of next tile (latency hides under compute+stores) ----
    float4 pf[4];
    if (it < NTILES - 1) {
      const float4* src = (const float4*)(x + (tt + 1) * (BM * 256));
#pragma unroll
      for (int i = 0; i < 4; ++i) pf[i] = src[i * 512 + tid];
    }

    // ---- compute: A from LDS, B from registers ----
    f32x4 acc[4];
#pragma unroll
    for (int n = 0; n < 4; ++n) acc[n] = (f32x4){0.f, 0.f, 0.f, 0.f};
#pragma unroll
    for (int kk = 0; kk < 8; ++kk) {
      const int arow = wm * 16 + lr;
      const int colb = (kk * 32 + lhi * 8) * 2;
      short8 a = *(const short8*)(cur + arow * 512 + (colb ^ ((arow & 7) << 4)));
#pragma unroll
      for (int n = 0; n < 4; ++n)
        acc[n] = __builtin_amdgcn_mfma_f32_16x16x32_bf16(a, Bf[kk][n], acc[n], 0, 0, 0);
    }

    // ---- store this tile (plain stores; spreads writes over time) ----
    {
      float* orow = out + (tt * BM + wm * 16 + lhi * 4) * 256;
#pragma unroll
      for (int n = 0; n < 4; ++n) {
        const int e = wn * 64 + n * 16 + lr;
#pragma unroll
        for (int r = 0; r < 4; ++r) orow[r * 256 + e] = acc[n][r] + bv[n];
      }
    }

    // ---- write next tile into the other buffer; single barrier ----
    if (it < NTILES - 1) {
#pragma unroll
      for (int i = 0; i < 4; ++i) {
        int f = i * 512 + tid;
        int row = f >> 6, colb = (f & 63) * 8;
        ushort4 p;
        p.x = __bfloat16_as_ushort(__float2bfloat16(pf[i].x));
        p.y = __bfloat16_as_ushort(__float2bfloat16(pf[i].y));
        p.z = __bfloat16_as_ushort(__float2bfloat16(pf[i].z));
        p.w = __bfloat16_as_ushort(__float2bfloat16(pf[i].w));
        *(ushort4*)(nxt + row * 512 + (colb ^ ((row & 7) << 4))) = p;
      }
    }
    __syncthreads();
  }
}

extern "C" void kernel_launch(void* const* d_in, const int* in_sizes, int n_in,
                              void* d_out, int out_size, void* d_ws, size_t ws_size,
                              hipStream_t stream) {
  const float* x = (const float*)d_in[0];     // (16, 8192, 256) fp32
  const float* W = (const float*)d_in[1];     // (256, 256) fp32
  const float* b = (const float*)d_in[2];     // (256,) fp32
  float* out = (float*)d_out;                 // (16, 8192, 256) fp32
  unsigned short* Wp = (unsigned short*)d_ws; // 256*256 bf16 = 128 KB

  haar_pack<<<64, 256, 0, stream>>>(W, Wp);

  const int grid = (out_size / 256) / (BM * NTILES);  // 131072 / 512 = 256
  wemb_gemm<<<grid, 512, 0, stream>>>(x, Wp, b, out);
}